// Round 1
// baseline (177.872 us; speedup 1.0000x reference)
//
#include <hip/hip_runtime.h>
#include <cmath>

#define TABLE_NUM 16
#define T_SIZE    4096
#define FEATF     2
#define Z_DIM     512
#define IMG       256
#define D_TAB     (TABLE_NUM * T_SIZE * FEATF)   // 131072
#define BATCH     8
#define HID       64
#define N_PIX     (IMG * IMG)                    // 65536
#define PRIME_Y   2654435761u

struct ResArr { float r[TABLE_NUM]; };

// ---------------------------------------------------------------------------
// Kernel 1: tables[b][n] = sum_k z[b][k] * w_table[k][n] + b_table[n]
// w_table is (512, 131072) row-major. Each thread: 2 consecutive n, all 8 b.
// Memory-bound on the single streaming read of w_table (268 MB).
// ---------------------------------------------------------------------------
__global__ __launch_bounds__(256) void gen_tables(
    const float* __restrict__ z, const float* __restrict__ w,
    const float* __restrict__ bt, float* __restrict__ tabs)
{
    __shared__ float zs[Z_DIM * BATCH];   // zs[k*8 + b]
    const int tid = threadIdx.x;

    // stage z (8 x 512) transposed into LDS; reads coalesced
    for (int i = tid; i < Z_DIM * BATCH; i += 256) {
        int b = i >> 9;          // i / 512
        int k = i & 511;
        zs[k * BATCH + b] = z[i];
    }
    __syncthreads();

    const int n0 = (blockIdx.x * 256 + tid) * 2;       // column pair
    float acc[BATCH][2];
#pragma unroll
    for (int b = 0; b < BATCH; ++b) { acc[b][0] = 0.f; acc[b][1] = 0.f; }

    const float2* wp = reinterpret_cast<const float2*>(w) + (n0 >> 1);
#pragma unroll 4
    for (int k = 0; k < Z_DIM; ++k) {
        float2 wv = wp[(size_t)k * (D_TAB / 2)];
#pragma unroll
        for (int b = 0; b < BATCH; ++b) {
            float zv = zs[k * BATCH + b];   // broadcast LDS read
            acc[b][0] = fmaf(zv, wv.x, acc[b][0]);
            acc[b][1] = fmaf(zv, wv.y, acc[b][1]);
        }
    }

    float2 bv = reinterpret_cast<const float2*>(bt)[n0 >> 1];
#pragma unroll
    for (int b = 0; b < BATCH; ++b) {
        float2 o;
        o.x = acc[b][0] + bv.x;
        o.y = acc[b][1] + bv.y;
        reinterpret_cast<float2*>(tabs)[(size_t)b * (D_TAB / 2) + (n0 >> 1)] = o;
    }
}

// ---------------------------------------------------------------------------
// Kernel 2: fused hash-grid lookup + 3-layer MLP + tanh, one pixel per thread.
// batch = blockIdx & 7 -> aligns batch with XCD (round-robin dispatch), so each
// XCD's L2 only caches that batch's 512 KB of tables.
// Per-thread scratch (feat 32 -> hidden 64) lives in a padded LDS slot
// (stride 65 floats => bank = (tid + k) % 32, 2 lanes/bank = conflict-free)
// so dynamic-k loops never runtime-index a register array.
// ---------------------------------------------------------------------------
__global__ __launch_bounds__(256) void hash_mlp(
    const float* __restrict__ tabs,
    const float* __restrict__ w1, const float* __restrict__ b1,
    const float* __restrict__ w2, const float* __restrict__ b2,
    const float* __restrict__ w3, const float* __restrict__ b3,
    float* __restrict__ out, ResArr res)
{
    __shared__ float hs[256 * 65];
    const int tid  = threadIdx.x;
    const int b    = blockIdx.x & 7;
    const int tile = blockIdx.x >> 3;
    const int n    = tile * 256 + tid;

    const float cx = ((float)(n >> 8)  + 0.5f) * (1.0f / IMG);
    const float cy = ((float)(n & 255) + 0.5f) * (1.0f / IMG);

    const float* tb   = tabs + (size_t)b * D_TAB;
    float*       slot = &hs[tid * 65];

    // ---- hash-grid features: 16 levels, 4-corner bilinear ----
    for (int l = 0; l < TABLE_NUM; ++l) {
        float r  = res.r[l];
        float px = cx * r, py = cy * r;
        float fx0 = floorf(px), fy0 = floorf(py);
        float fx = px - fx0, fy = py - fy0;
        unsigned x0 = (unsigned)(int)fx0, y0 = (unsigned)(int)fy0;
        unsigned x1 = x0 + 1u, y1 = y0 + 1u;
        unsigned hy0 = y0 * PRIME_Y, hy1 = y1 * PRIME_Y;
        unsigned i00 = (x0 ^ hy0) & (T_SIZE - 1);
        unsigned i10 = (x1 ^ hy0) & (T_SIZE - 1);
        unsigned i01 = (x0 ^ hy1) & (T_SIZE - 1);
        unsigned i11 = (x1 ^ hy1) & (T_SIZE - 1);
        const float2* tl = reinterpret_cast<const float2*>(tb + l * T_SIZE * FEATF);
        float2 f00 = tl[i00], f10 = tl[i10], f01 = tl[i01], f11 = tl[i11];
        float w00 = (1.f - fx) * (1.f - fy);
        float w10 = fx * (1.f - fy);
        float w01 = (1.f - fx) * fy;
        float w11 = fx * fy;
        slot[2 * l]     = f00.x * w00 + f10.x * w10 + f01.x * w01 + f11.x * w11;
        slot[2 * l + 1] = f00.y * w00 + f10.y * w10 + f01.y * w01 + f11.y * w11;
    }

    // ---- layer 1: 32 -> 64, relu ----
    float h[HID];
#pragma unroll
    for (int j = 0; j < HID; ++j) h[j] = b1[j];
    for (int k = 0; k < TABLE_NUM * FEATF; ++k) {
        float f = slot[k];
        const float* wr = w1 + k * HID;    // uniform -> scalar loads
#pragma unroll
        for (int j = 0; j < HID; ++j) h[j] = fmaf(f, wr[j], h[j]);
    }
#pragma unroll
    for (int j = 0; j < HID; ++j) slot[j] = fmaxf(h[j], 0.f);  // relu -> LDS

    // ---- layer 2: 64 -> 64, relu ----
    float g[HID];
#pragma unroll
    for (int j = 0; j < HID; ++j) g[j] = b2[j];
    for (int k = 0; k < HID; ++k) {
        float f = slot[k];
        const float* wr = w2 + k * HID;
#pragma unroll
        for (int j = 0; j < HID; ++j) g[j] = fmaf(f, wr[j], g[j]);
    }
#pragma unroll
    for (int j = 0; j < HID; ++j) g[j] = fmaxf(g[j], 0.f);

    // ---- layer 3: 64 -> 3, tanh ----
    float o0 = b3[0], o1 = b3[1], o2 = b3[2];
#pragma unroll
    for (int k = 0; k < HID; ++k) {
        float f = g[k];
        o0 = fmaf(f, w3[k * 3 + 0], o0);
        o1 = fmaf(f, w3[k * 3 + 1], o1);
        o2 = fmaf(f, w3[k * 3 + 2], o2);
    }
    o0 = tanhf(o0); o1 = tanhf(o1); o2 = tanhf(o2);

    // out shape (B, 3, 256, 256); n = i*256 + j already matches (i,j) order
    size_t base = (size_t)b * 3 * N_PIX + n;
    out[base]             = o0;
    out[base + N_PIX]     = o1;
    out[base + 2 * N_PIX] = o2;
}

extern "C" void kernel_launch(void* const* d_in, const int* in_sizes, int n_in,
                              void* d_out, int out_size, void* d_ws, size_t ws_size,
                              hipStream_t stream)
{
    const float* z  = (const float*)d_in[0];
    const float* wt = (const float*)d_in[1];
    const float* bt = (const float*)d_in[2];
    const float* w1 = (const float*)d_in[3];
    const float* b1 = (const float*)d_in[4];
    const float* w2 = (const float*)d_in[5];
    const float* b2 = (const float*)d_in[6];
    const float* w3 = (const float*)d_in[7];
    const float* b3 = (const float*)d_in[8];
    float* out  = (float*)d_out;
    float* tabs = (float*)d_ws;            // 8 * 131072 * 4 B = 4 MB

    // res_l = float32(16 * growth^l), growth computed in f64 exactly like numpy
    ResArr ra;
    const double growth = std::exp((std::log(256.0) - std::log(16.0)) / 15.0);
    for (int l = 0; l < TABLE_NUM; ++l)
        ra.r[l] = (float)(16.0 * std::pow(growth, (double)l));

    // kernel 1: 131072 cols / 2 per thread / 256 per block = 256 blocks
    gen_tables<<<D_TAB / 2 / 256, 256, 0, stream>>>(z, wt, bt, tabs);

    // kernel 2: 8 batches * 256 tiles = 2048 blocks
    hash_mlp<<<BATCH * (N_PIX / 256), 256, 0, stream>>>(
        tabs, w1, b1, w2, b2, w3, b3, out, ra);
}

// Round 2
// 118.636 us; speedup vs baseline: 1.4993x; 1.4993x over previous
//
#include <hip/hip_runtime.h>
#include <cmath>

#define TABLE_NUM 16
#define T_SIZE    4096
#define FEATF     2
#define Z_DIM     512
#define IMG       256
#define D_TAB     (TABLE_NUM * T_SIZE * FEATF)   // 131072
#define BATCH     8
#define HID       64
#define N_PIX     (IMG * IMG)                    // 65536
#define PRIME_Y   2654435761u

typedef _Float16 v8h  __attribute__((ext_vector_type(8)));
typedef _Float16 v2h  __attribute__((ext_vector_type(2)));
typedef float    v4f  __attribute__((ext_vector_type(4)));

struct ResArr { float r[TABLE_NUM]; };

// ---------------------------------------------------------------------------
// Kernel 0: transpose + f16-cast the MLP weights into MFMA-friendly [n][k]
// layout. w3 padded to 16 output cols. Tiny; runs once per launch.
// ---------------------------------------------------------------------------
__global__ void prep_weights(const float* __restrict__ w1, const float* __restrict__ w2,
                             const float* __restrict__ w3,
                             _Float16* __restrict__ w1T, _Float16* __restrict__ w2T,
                             _Float16* __restrict__ w3T)
{
    const int t = threadIdx.x;
    for (int i = t; i < HID * 32; i += 256) {          // w1T[64][32] <- w1[32][64]
        int n = i >> 5, k = i & 31;
        w1T[i] = (_Float16)w1[k * HID + n];
    }
    for (int i = t; i < HID * HID; i += 256) {         // w2T[64][64] <- w2[64][64]
        int n = i >> 6, k = i & 63;
        w2T[i] = (_Float16)w2[k * HID + n];
    }
    for (int i = t; i < 16 * HID; i += 256) {          // w3T[16][64] <- w3[64][3], pad
        int n = i >> 6, k = i & 63;
        w3T[i] = (_Float16)(n < 3 ? w3[k * 3 + n] : 0.f);
    }
}

// ---------------------------------------------------------------------------
// Kernel 1: tables[b][n] = sum_k z[b][k] * w_table[k][n] + b_table[n]
// Memory-bound stream of w_table (268 MB). z reads are block-uniform ->
// scalar-cache s_loads (no LDS). unroll 16 -> 16 float2 loads in flight per
// wave (4 waves/CU * 8 KB = 32 KB >> 9.2 KB latency-BW product).
// ---------------------------------------------------------------------------
__global__ __launch_bounds__(256) void gen_tables(
    const float* __restrict__ z, const float* __restrict__ w,
    const float* __restrict__ bt, float* __restrict__ tabs)
{
    const int n0 = (blockIdx.x * 256 + threadIdx.x) * 2;
    const float2* wp = reinterpret_cast<const float2*>(w) + (n0 >> 1);

    float acc[BATCH][2];
#pragma unroll
    for (int b = 0; b < BATCH; ++b) { acc[b][0] = 0.f; acc[b][1] = 0.f; }

#pragma unroll 16
    for (int k = 0; k < Z_DIM; ++k) {
        float2 wv = wp[(size_t)k * (D_TAB / 2)];
#pragma unroll
        for (int b = 0; b < BATCH; ++b) {
            float zv = z[b * Z_DIM + k];       // uniform -> s_load
            acc[b][0] = fmaf(zv, wv.x, acc[b][0]);
            acc[b][1] = fmaf(zv, wv.y, acc[b][1]);
        }
    }

    float2 bv = reinterpret_cast<const float2*>(bt)[n0 >> 1];
#pragma unroll
    for (int b = 0; b < BATCH; ++b) {
        float2 o;
        o.x = acc[b][0] + bv.x;
        o.y = acc[b][1] + bv.y;
        reinterpret_cast<float2*>(tabs)[(size_t)b * (D_TAB / 2) + (n0 >> 1)] = o;
    }
}

// ---------------------------------------------------------------------------
// Kernel 2: hash-grid lookup (f32 VALU) + 3-layer MLP on f16 MFMA.
// Block = 256 threads = 4 waves; each wave owns 64 pixels.
// batch = blockIdx & 7 aligns batch with XCD round-robin -> each XCD L2 holds
// one batch's 512 KB of tables.
// Fragment redistribution through per-wave LDS buf[64][72] f16:
//   row stride 144 B -> bank = 4*row mod 32 -> <=2-way on b128 reads (free).
// MFMA layouts (16x16x32): A row=lane&15, k=(lane>>4)*8+e (8 contiguous k);
// B col=lane&15, same k; C/D col=lane&15, row=(lane>>4)*4+e  [m89].
// ---------------------------------------------------------------------------
__global__ __launch_bounds__(256) void hash_mlp(
    const float* __restrict__ tabs,
    const _Float16* __restrict__ w1T, const _Float16* __restrict__ w2T,
    const _Float16* __restrict__ w3T,
    const float* __restrict__ b1, const float* __restrict__ b2,
    const float* __restrict__ b3,
    float* __restrict__ out, ResArr res)
{
    __shared__ _Float16 buf[4][64][72];
    const int tid  = threadIdx.x;
    const int wid  = tid >> 6;
    const int lane = tid & 63;
    const int b    = blockIdx.x & 7;
    const int tile = blockIdx.x >> 3;
    const int n    = tile * 256 + tid;          // this thread's pixel

    const float cx = ((float)(n >> 8)  + 0.5f) * (1.0f / IMG);
    const float cy = ((float)(n & 255) + 0.5f) * (1.0f / IMG);
    const float* tb = tabs + (size_t)b * D_TAB;

    // ---- hash-grid features: 16 levels, write f16 pairs straight to LDS ----
#pragma unroll 4
    for (int l = 0; l < TABLE_NUM; ++l) {
        float r  = res.r[l];
        float px = cx * r, py = cy * r;
        float fx0 = floorf(px), fy0 = floorf(py);
        float fx = px - fx0, fy = py - fy0;
        unsigned x0 = (unsigned)(int)fx0, y0 = (unsigned)(int)fy0;
        unsigned hy0 = y0 * PRIME_Y, hy1 = (y0 + 1u) * PRIME_Y;
        unsigned i00 = (x0 ^ hy0) & (T_SIZE - 1);
        unsigned i10 = ((x0 + 1u) ^ hy0) & (T_SIZE - 1);
        unsigned i01 = (x0 ^ hy1) & (T_SIZE - 1);
        unsigned i11 = ((x0 + 1u) ^ hy1) & (T_SIZE - 1);
        const float2* tl = reinterpret_cast<const float2*>(tb + l * T_SIZE * FEATF);
        float2 f00 = tl[i00], f10 = tl[i10], f01 = tl[i01], f11 = tl[i11];
        float w00 = (1.f - fx) * (1.f - fy);
        float w10 = fx * (1.f - fy);
        float w01 = (1.f - fx) * fy;
        float w11 = fx * fy;
        float e0 = f00.x * w00 + f10.x * w10 + f01.x * w01 + f11.x * w11;
        float e1 = f00.y * w00 + f10.y * w10 + f01.y * w01 + f11.y * w11;
        v2h p; p.x = (_Float16)e0; p.y = (_Float16)e1;
        *reinterpret_cast<v2h*>(&buf[wid][lane][2 * l]) = p;
    }
    __syncthreads();

    const int arow = lane & 15;        // A row / B col / C col
    const int kgrp = lane >> 4;        // k-group

    // ---- layer 1: 32 -> 64  (K=32 = one MFMA) ----
    v8h a1[4];
#pragma unroll
    for (int mt = 0; mt < 4; ++mt)
        a1[mt] = *reinterpret_cast<const v8h*>(&buf[wid][mt * 16 + arow][kgrp * 8]);

    v4f c1[4][4];
#pragma unroll
    for (int nt = 0; nt < 4; ++nt) {
        v8h bf = *reinterpret_cast<const v8h*>(&w1T[(nt * 16 + arow) * 32 + kgrp * 8]);
        float bias = b1[nt * 16 + arow];
#pragma unroll
        for (int mt = 0; mt < 4; ++mt) {
            v4f c = {0.f, 0.f, 0.f, 0.f};
            c = __builtin_amdgcn_mfma_f32_16x16x32_f16(a1[mt], bf, c, 0, 0, 0);
#pragma unroll
            for (int e = 0; e < 4; ++e)
                c1[mt][nt][e] = fmaxf(c[e] + bias, 0.f);
        }
    }
    __syncthreads();                    // feat reads done before h1 overwrite

    // write h1 -> buf rows=pixel, cols=hidden
#pragma unroll
    for (int mt = 0; mt < 4; ++mt)
#pragma unroll
        for (int nt = 0; nt < 4; ++nt)
#pragma unroll
            for (int e = 0; e < 4; ++e)
                buf[wid][mt * 16 + kgrp * 4 + e][nt * 16 + arow] = (_Float16)c1[mt][nt][e];
    __syncthreads();

    // ---- layer 2: 64 -> 64  (K=64 = 2 MFMA) ----
    v8h a2[4][2];
#pragma unroll
    for (int mt = 0; mt < 4; ++mt)
#pragma unroll
        for (int kc = 0; kc < 2; ++kc)
            a2[mt][kc] = *reinterpret_cast<const v8h*>(&buf[wid][mt * 16 + arow][kc * 32 + kgrp * 8]);

    v4f c2[4][4];
#pragma unroll
    for (int nt = 0; nt < 4; ++nt) {
        v8h bf0 = *reinterpret_cast<const v8h*>(&w2T[(nt * 16 + arow) * 64 + kgrp * 8]);
        v8h bf1 = *reinterpret_cast<const v8h*>(&w2T[(nt * 16 + arow) * 64 + 32 + kgrp * 8]);
        float bias = b2[nt * 16 + arow];
#pragma unroll
        for (int mt = 0; mt < 4; ++mt) {
            v4f c = {0.f, 0.f, 0.f, 0.f};
            c = __builtin_amdgcn_mfma_f32_16x16x32_f16(a2[mt][0], bf0, c, 0, 0, 0);
            c = __builtin_amdgcn_mfma_f32_16x16x32_f16(a2[mt][1], bf1, c, 0, 0, 0);
#pragma unroll
            for (int e = 0; e < 4; ++e)
                c2[mt][nt][e] = fmaxf(c[e] + bias, 0.f);
        }
    }
    __syncthreads();                    // h1 reads done before h2 overwrite

#pragma unroll
    for (int mt = 0; mt < 4; ++mt)
#pragma unroll
        for (int nt = 0; nt < 4; ++nt)
#pragma unroll
            for (int e = 0; e < 4; ++e)
                buf[wid][mt * 16 + kgrp * 4 + e][nt * 16 + arow] = (_Float16)c2[mt][nt][e];
    __syncthreads();

    // ---- layer 3: 64 -> 3 (padded to 16), tanh, store ----
    v8h b3f0 = *reinterpret_cast<const v8h*>(&w3T[arow * 64 + kgrp * 8]);
    v8h b3f1 = *reinterpret_cast<const v8h*>(&w3T[arow * 64 + 32 + kgrp * 8]);
    const int ch = arow;                // output channel for this lane
    const float bias3 = (ch < 3) ? b3[ch] : 0.f;

#pragma unroll
    for (int mt = 0; mt < 4; ++mt) {
        v8h a0 = *reinterpret_cast<const v8h*>(&buf[wid][mt * 16 + arow][kgrp * 8]);
        v8h a1v = *reinterpret_cast<const v8h*>(&buf[wid][mt * 16 + arow][32 + kgrp * 8]);
        v4f c = {0.f, 0.f, 0.f, 0.f};
        c = __builtin_amdgcn_mfma_f32_16x16x32_f16(a0, b3f0, c, 0, 0, 0);
        c = __builtin_amdgcn_mfma_f32_16x16x32_f16(a1v, b3f1, c, 0, 0, 0);
        if (ch < 3) {
            float4 st;
            st.x = tanhf(c[0] + bias3);
            st.y = tanhf(c[1] + bias3);
            st.z = tanhf(c[2] + bias3);
            st.w = tanhf(c[3] + bias3);
            size_t idx = ((size_t)b * 3 + ch) * N_PIX + tile * 256 + wid * 64 + mt * 16 + kgrp * 4;
            *reinterpret_cast<float4*>(&out[idx]) = st;
        }
    }
}

extern "C" void kernel_launch(void* const* d_in, const int* in_sizes, int n_in,
                              void* d_out, int out_size, void* d_ws, size_t ws_size,
                              hipStream_t stream)
{
    const float* z  = (const float*)d_in[0];
    const float* wt = (const float*)d_in[1];
    const float* bt = (const float*)d_in[2];
    const float* w1 = (const float*)d_in[3];
    const float* b1 = (const float*)d_in[4];
    const float* w2 = (const float*)d_in[5];
    const float* b2 = (const float*)d_in[6];
    const float* w3 = (const float*)d_in[7];
    const float* b3 = (const float*)d_in[8];
    float* out  = (float*)d_out;

    char* ws = (char*)d_ws;
    float*     tabs = (float*)ws;                        // 4 MB
    _Float16*  w1T  = (_Float16*)(ws + (4 << 20));       // 4 KB
    _Float16*  w2T  = (_Float16*)(ws + (4 << 20) + 4096);  // 8 KB
    _Float16*  w3T  = (_Float16*)(ws + (4 << 20) + 12288); // 2 KB

    ResArr ra;
    const double growth = std::exp((std::log(256.0) - std::log(16.0)) / 15.0);
    for (int l = 0; l < TABLE_NUM; ++l)
        ra.r[l] = (float)(16.0 * std::pow(growth, (double)l));

    prep_weights<<<1, 256, 0, stream>>>(w1, w2, w3, w1T, w2T, w3T);
    gen_tables<<<D_TAB / 2 / 256, 256, 0, stream>>>(z, wt, bt, tabs);
    hash_mlp<<<BATCH * (N_PIX / 256), 256, 0, stream>>>(
        tabs, w1T, w2T, w3T, b1, b2, b3, out, ra);
}